// Round 1
// baseline (1421.717 us; speedup 1.0000x reference)
//
#include <hip/hip_runtime.h>
#include <hip/hip_bf16.h>

constexpr int D  = 128;   // feature dim = K = UNITS
constexpr int BM = 64;    // nodes per block in GEMM
constexpr int BMP = BM + 1; // padded LDS stride for transposed X tile

// ---------------------------------------------------------------------------
// Kernel 1: h = sigmoid(x @ W_gate + b) * (x @ W)   [N, 128]
// Block: 256 threads, tile = 64 nodes x 128 feats, thread tile = 4 nodes x 8 feats
// ---------------------------------------------------------------------------
__global__ __launch_bounds__(256, 1) void fused_gemm_gate(
    const float* __restrict__ x, const float* __restrict__ W,
    const float* __restrict__ Wg, const float* __restrict__ bg,
    float* __restrict__ h, int n_nodes)
{
    __shared__ float Ws[D * D];       // W staged as-is: [k][f], 64 KB
    __shared__ float Xt[D * BMP];     // X tile transposed: [k][n], padded
    __shared__ float Gs[BM];          // per-node gate

    const int t = threadIdx.x;
    const int node0 = blockIdx.x * BM;

    // stage W (64 KB) via float4
    {
        const float4* src = (const float4*)W;
        float4* dst = (float4*)Ws;
        #pragma unroll
        for (int i = t; i < D * D / 4; i += 256) dst[i] = src[i];
    }
    // stage X tile transposed: thread i loads float4 along k of one node
    {
        for (int i = t; i < BM * (D / 4); i += 256) {
            int n  = i >> 5;          // D/4 = 32 quads per node
            int kq = i & 31;
            int node = node0 + n;
            float4 v = make_float4(0.f, 0.f, 0.f, 0.f);
            if (node < n_nodes) v = *(const float4*)(x + (size_t)node * D + kq * 4);
            Xt[(kq * 4 + 0) * BMP + n] = v.x;
            Xt[(kq * 4 + 1) * BMP + n] = v.y;
            Xt[(kq * 4 + 2) * BMP + n] = v.z;
            Xt[(kq * 4 + 3) * BMP + n] = v.w;
        }
    }
    __syncthreads();

    // gates: threads 0..63 each compute dot(x[node], Wg)
    if (t < BM) {
        float gp = 0.f;
        #pragma unroll 8
        for (int k = 0; k < D; ++k) gp += Xt[k * BMP + t] * Wg[k];
        Gs[t] = 1.f / (1.f + __expf(-(gp + bg[0])));
    }
    __syncthreads();

    // main compute: thread tile 4 nodes x 8 feats
    const int tf = t & 15;            // feat group: feats tf*8 .. tf*8+7
    const int tn = t >> 4;            // node group: nodes tn*4 .. tn*4+3
    const int f0 = tf * 8;
    const int n0 = tn * 4;

    float acc[4][8];
    #pragma unroll
    for (int i = 0; i < 4; ++i)
        #pragma unroll
        for (int j = 0; j < 8; ++j) acc[i][j] = 0.f;

    #pragma unroll 4
    for (int k = 0; k < D; ++k) {
        float4 xv = *(const float4*)&Xt[k * BMP + n0];
        float4 wa = *(const float4*)&Ws[k * D + f0];
        float4 wb = *(const float4*)&Ws[k * D + f0 + 4];
        float xr[4] = {xv.x, xv.y, xv.z, xv.w};
        float wr[8] = {wa.x, wa.y, wa.z, wa.w, wb.x, wb.y, wb.z, wb.w};
        #pragma unroll
        for (int i = 0; i < 4; ++i)
            #pragma unroll
            for (int j = 0; j < 8; ++j)
                acc[i][j] += xr[i] * wr[j];
    }

    // epilogue: h = g * acc
    #pragma unroll
    for (int i = 0; i < 4; ++i) {
        int node = node0 + n0 + i;
        if (node >= n_nodes) continue;
        float g = Gs[n0 + i];
        float4 o0 = make_float4(acc[i][0] * g, acc[i][1] * g, acc[i][2] * g, acc[i][3] * g);
        float4 o1 = make_float4(acc[i][4] * g, acc[i][5] * g, acc[i][6] * g, acc[i][7] * g);
        float* hp = h + (size_t)node * D + f0;
        *(float4*)(hp)     = o0;
        *(float4*)(hp + 4) = o1;
    }
}

// ---------------------------------------------------------------------------
// Kernel 2: out[row[e]] += vals[e] * h[col[e]]  via f32 atomics.
// One wave (64 lanes) per edge; each lane handles 2 consecutive feats.
// ---------------------------------------------------------------------------
__global__ __launch_bounds__(256) void scatter_edges(
    const int* __restrict__ er, const int* __restrict__ ec,
    const float* __restrict__ ev, const float* __restrict__ h,
    float* __restrict__ out, int n_edges)
{
    int gw   = (blockIdx.x * 256 + threadIdx.x) >> 6;  // global wave id = edge id
    int lane = threadIdx.x & 63;
    if (gw >= n_edges) return;
    int r = er[gw];
    int c = ec[gw];
    float v = ev[gw];
    const float2 hv = *(const float2*)(h + (size_t)c * D + lane * 2);
    float* op = out + (size_t)r * D + lane * 2;
    atomicAdd(op,     v * hv.x);
    atomicAdd(op + 1, v * hv.y);
}

extern "C" void kernel_launch(void* const* d_in, const int* in_sizes, int n_in,
                              void* d_out, int out_size, void* d_ws, size_t ws_size,
                              hipStream_t stream) {
    const float* x  = (const float*)d_in[0];
    const int*   er = (const int*)d_in[1];
    const int*   ec = (const int*)d_in[2];
    const float* ev = (const float*)d_in[3];
    const float* W  = (const float*)d_in[4];
    const float* Wg = (const float*)d_in[5];
    const float* bg = (const float*)d_in[6];
    float* out = (float*)d_out;
    float* h   = (float*)d_ws;          // [n_nodes, 128] = 51.2 MB scratch

    const int n_nodes = in_sizes[0] / D;
    const int n_edges = in_sizes[1];

    // zero the (poisoned) output accumulator
    hipMemsetAsync(d_out, 0, (size_t)out_size * sizeof(float), stream);

    // h = gate(x) * (x @ W)
    dim3 gemm_grid((n_nodes + BM - 1) / BM);
    fused_gemm_gate<<<gemm_grid, 256, 0, stream>>>(x, W, Wg, bg, h, n_nodes);

    // scatter-accumulate over edges
    int blocks = (n_edges + 3) / 4;     // 4 waves (edges) per 256-thread block
    scatter_edges<<<blocks, 256, 0, stream>>>(er, ec, ev, h, out, n_edges);
}

// Round 2
// 419.688 us; speedup vs baseline: 3.3876x; 3.3876x over previous
//
#include <hip/hip_runtime.h>
#include <hip/hip_bf16.h>

constexpr int D   = 128;     // feature dim = K = UNITS
constexpr int BM  = 64;      // nodes per block in GEMM
constexpr int BMP = BM + 1;  // padded LDS stride for transposed X tile

// ---------------------------------------------------------------------------
// Kernel 1: h = sigmoid(x @ W_gate + b) * (x @ W)   [N, 128]
// ---------------------------------------------------------------------------
__global__ __launch_bounds__(256, 1) void fused_gemm_gate(
    const float* __restrict__ x, const float* __restrict__ W,
    const float* __restrict__ Wg, const float* __restrict__ bg,
    float* __restrict__ h, int n_nodes)
{
    __shared__ float Ws[D * D];       // W staged: [k][f], 64 KB
    __shared__ float Xt[D * BMP];     // X tile transposed: [k][n], padded
    __shared__ float Gs[BM];          // per-node gate

    const int t = threadIdx.x;
    const int node0 = blockIdx.x * BM;

    {   // stage W via float4
        const float4* src = (const float4*)W;
        float4* dst = (float4*)Ws;
        #pragma unroll
        for (int i = t; i < D * D / 4; i += 256) dst[i] = src[i];
    }
    {   // stage X tile transposed
        for (int i = t; i < BM * (D / 4); i += 256) {
            int n  = i >> 5;
            int kq = i & 31;
            int node = node0 + n;
            float4 v = make_float4(0.f, 0.f, 0.f, 0.f);
            if (node < n_nodes) v = *(const float4*)(x + (size_t)node * D + kq * 4);
            Xt[(kq * 4 + 0) * BMP + n] = v.x;
            Xt[(kq * 4 + 1) * BMP + n] = v.y;
            Xt[(kq * 4 + 2) * BMP + n] = v.z;
            Xt[(kq * 4 + 3) * BMP + n] = v.w;
        }
    }
    __syncthreads();

    if (t < BM) {  // gates
        float gp = 0.f;
        #pragma unroll 8
        for (int k = 0; k < D; ++k) gp += Xt[k * BMP + t] * Wg[k];
        Gs[t] = 1.f / (1.f + __expf(-(gp + bg[0])));
    }
    __syncthreads();

    const int tf = t & 15;
    const int tn = t >> 4;
    const int f0 = tf * 8;
    const int n0 = tn * 4;

    float acc[4][8];
    #pragma unroll
    for (int i = 0; i < 4; ++i)
        #pragma unroll
        for (int j = 0; j < 8; ++j) acc[i][j] = 0.f;

    #pragma unroll 4
    for (int k = 0; k < D; ++k) {
        float4 xv = *(const float4*)&Xt[k * BMP + n0];
        float4 wa = *(const float4*)&Ws[k * D + f0];
        float4 wb = *(const float4*)&Ws[k * D + f0 + 4];
        float xr[4] = {xv.x, xv.y, xv.z, xv.w};
        float wr[8] = {wa.x, wa.y, wa.z, wa.w, wb.x, wb.y, wb.z, wb.w};
        #pragma unroll
        for (int i = 0; i < 4; ++i)
            #pragma unroll
            for (int j = 0; j < 8; ++j)
                acc[i][j] += xr[i] * wr[j];
    }

    #pragma unroll
    for (int i = 0; i < 4; ++i) {
        int node = node0 + n0 + i;
        if (node >= n_nodes) continue;
        float g = Gs[n0 + i];
        float4 o0 = make_float4(acc[i][0] * g, acc[i][1] * g, acc[i][2] * g, acc[i][3] * g);
        float4 o1 = make_float4(acc[i][4] * g, acc[i][5] * g, acc[i][6] * g, acc[i][7] * g);
        float* hp = h + (size_t)node * D + f0;
        *(float4*)(hp)     = o0;
        *(float4*)(hp + 4) = o1;
    }
}

// ---------------------------------------------------------------------------
// CSR-building pipeline: histogram -> exclusive scan (2-level) -> scatter
// ---------------------------------------------------------------------------
__global__ __launch_bounds__(256) void hist_rows(
    const int* __restrict__ er, int* __restrict__ cnt, int n_edges)
{
    int e = blockIdx.x * 256 + threadIdx.x;
    if (e < n_edges) atomicAdd(&cnt[er[e]], 1);
}

// pass1: per-block (1024 elems) sums
__global__ __launch_bounds__(256) void scan_pass1(
    const int* __restrict__ cnt, int* __restrict__ partials, int n)
{
    __shared__ int red[256];
    int t = threadIdx.x;
    int base = blockIdx.x * 1024 + t * 4;
    int s = 0;
    #pragma unroll
    for (int j = 0; j < 4; ++j)
        if (base + j < n) s += cnt[base + j];
    red[t] = s;
    __syncthreads();
    for (int off = 128; off > 0; off >>= 1) {
        if (t < off) red[t] += red[t + off];
        __syncthreads();
    }
    if (t == 0) partials[blockIdx.x] = red[0];
}

// pass2: serial exclusive scan of the (<=128) block partials
__global__ void scan_pass2(int* __restrict__ partials, int nblk)
{
    if (blockIdx.x == 0 && threadIdx.x == 0) {
        int run = 0;
        for (int i = 0; i < nblk; ++i) {
            int v = partials[i];
            partials[i] = run;
            run += v;
        }
    }
}

// pass3: per-block exclusive scan + block offset; writes start[] and fill[]
__global__ __launch_bounds__(256) void scan_pass3(
    const int* __restrict__ cnt, const int* __restrict__ partials,
    int* __restrict__ start, int* __restrict__ fill, int n, int n_edges)
{
    __shared__ int wtot[4];
    int t = threadIdx.x;
    int lane = t & 63, w = t >> 6;
    int base = blockIdx.x * 1024 + t * 4;
    int v[4];
    int tsum = 0;
    #pragma unroll
    for (int j = 0; j < 4; ++j) {
        v[j] = (base + j < n) ? cnt[base + j] : 0;
        tsum += v[j];
    }
    // wave inclusive scan of tsum
    int x = tsum;
    #pragma unroll
    for (int d = 1; d < 64; d <<= 1) {
        int y = __shfl_up(x, d);
        if (lane >= d) x += y;
    }
    int pre = x - tsum;               // exclusive within wave
    if (lane == 63) wtot[w] = x;      // wave total
    __syncthreads();
    int woff = 0;
    for (int i = 0; i < w; ++i) woff += wtot[i];
    int run = partials[blockIdx.x] + woff + pre;
    #pragma unroll
    for (int j = 0; j < 4; ++j) {
        if (base + j < n) {
            start[base + j] = run;
            fill[base + j]  = run;
            run += v[j];
        }
    }
    if (blockIdx.x == 0 && t == 0) start[n] = n_edges;
}

__global__ __launch_bounds__(256) void scatter_sort(
    const int* __restrict__ er, const int* __restrict__ ec,
    const float* __restrict__ ev, int* __restrict__ fill,
    int2* __restrict__ sorted, int n_edges)
{
    int e = blockIdx.x * 256 + threadIdx.x;
    if (e >= n_edges) return;
    int r = er[e];
    int pos = atomicAdd(&fill[r], 1);
    sorted[pos] = make_int2(ec[e], __float_as_int(ev[e]));
}

// ---------------------------------------------------------------------------
// Gather-reduce: one wave per row; lane l owns feats {2l, 2l+1}.
// ---------------------------------------------------------------------------
__global__ __launch_bounds__(256) void gather_rows(
    const int* __restrict__ start, const int2* __restrict__ sorted,
    const float* __restrict__ h, float* __restrict__ out, int n_nodes)
{
    int row  = (blockIdx.x * 256 + threadIdx.x) >> 6;
    int lane = threadIdx.x & 63;
    if (row >= n_nodes) return;
    int s = start[row];
    int e = start[row + 1];
    float2 acc = make_float2(0.f, 0.f);
    for (int base = s; base < e; base += 64) {
        int idx = base + lane;
        int2 pk = (idx < e) ? sorted[idx] : make_int2(0, 0);
        int m = e - base; if (m > 64) m = 64;
        for (int j = 0; j < m; ++j) {
            int   col = __shfl(pk.x, j);
            float v   = __int_as_float(__shfl(pk.y, j));
            const float2 hv = *(const float2*)(h + (size_t)col * D + lane * 2);
            acc.x += v * hv.x;
            acc.y += v * hv.y;
        }
    }
    *(float2*)(out + (size_t)row * D + lane * 2) = acc;
}

// ---------------------------------------------------------------------------
// Fallback (small ws): atomic scatter, as in R1
// ---------------------------------------------------------------------------
__global__ __launch_bounds__(256) void scatter_edges(
    const int* __restrict__ er, const int* __restrict__ ec,
    const float* __restrict__ ev, const float* __restrict__ h,
    float* __restrict__ out, int n_edges)
{
    int gw   = (blockIdx.x * 256 + threadIdx.x) >> 6;
    int lane = threadIdx.x & 63;
    if (gw >= n_edges) return;
    int r = er[gw];
    int c = ec[gw];
    float v = ev[gw];
    const float2 hv = *(const float2*)(h + (size_t)c * D + lane * 2);
    float* op = out + (size_t)r * D + lane * 2;
    atomicAdd(op,     v * hv.x);
    atomicAdd(op + 1, v * hv.y);
}

extern "C" void kernel_launch(void* const* d_in, const int* in_sizes, int n_in,
                              void* d_out, int out_size, void* d_ws, size_t ws_size,
                              hipStream_t stream) {
    const float* x  = (const float*)d_in[0];
    const int*   er = (const int*)d_in[1];
    const int*   ec = (const int*)d_in[2];
    const float* ev = (const float*)d_in[3];
    const float* W  = (const float*)d_in[4];
    const float* Wg = (const float*)d_in[5];
    const float* bg = (const float*)d_in[6];
    float* out = (float*)d_out;

    const int n_nodes = in_sizes[0] / D;
    const int n_edges = in_sizes[1];

    // workspace layout
    char* ws = (char*)d_ws;
    size_t off = 0;
    auto alloc = [&](size_t bytes) {
        char* p = ws + off;
        off += (bytes + 15) & ~size_t(15);
        return p;
    };
    float* h        = (float*)alloc((size_t)n_nodes * D * sizeof(float));
    int2*  sorted   = (int2*) alloc((size_t)n_edges * sizeof(int2));
    int*   startArr = (int*)  alloc((size_t)(n_nodes + 1) * sizeof(int));
    int*   cnt      = (int*)  alloc((size_t)n_nodes * sizeof(int));
    int*   fill     = (int*)  alloc((size_t)n_nodes * sizeof(int));
    int*   partials = (int*)  alloc(128 * sizeof(int));
    bool have_ws = off <= ws_size;

    // h = gate(x) * (x @ W)
    dim3 gemm_grid((n_nodes + BM - 1) / BM);
    fused_gemm_gate<<<gemm_grid, 256, 0, stream>>>(x, W, Wg, bg, h, n_nodes);

    if (have_ws) {
        // build CSR via counting sort
        hipMemsetAsync(cnt, 0, (size_t)n_nodes * sizeof(int), stream);
        int eb = (n_edges + 255) / 256;
        hist_rows<<<eb, 256, 0, stream>>>(er, cnt, n_edges);
        int nblk = (n_nodes + 1023) / 1024;
        scan_pass1<<<nblk, 256, 0, stream>>>(cnt, partials, n_nodes);
        scan_pass2<<<1, 64, 0, stream>>>(partials, nblk);
        scan_pass3<<<nblk, 256, 0, stream>>>(cnt, partials, startArr, fill, n_nodes, n_edges);
        scatter_sort<<<eb, 256, 0, stream>>>(er, ec, ev, fill, sorted, n_edges);
        // gather-reduce, one wave per row
        int rb = (n_nodes * 64 + 255) / 256;
        gather_rows<<<rb, 256, 0, stream>>>(startArr, sorted, h, out, n_nodes);
    } else {
        hipMemsetAsync(d_out, 0, (size_t)out_size * sizeof(float), stream);
        int blocks = (n_edges + 3) / 4;
        scatter_edges<<<blocks, 256, 0, stream>>>(er, ec, ev, h, out, n_edges);
    }
}

// Round 3
// 324.377 us; speedup vs baseline: 4.3829x; 1.2938x over previous
//
#include <hip/hip_runtime.h>
#include <hip/hip_bf16.h>

constexpr int D       = 128;   // feature dim = K = UNITS
constexpr int BM      = 64;    // nodes per block in GEMM
constexpr int BMP     = BM + 1;
constexpr int CHUNK   = 4096;  // edges per binning block
constexpr int NBKT_PAD = 512;  // padded bucket count (actual = ceil(N/256) = 391)
constexpr int BKT_CAP = 6144;  // fine-sort LDS capacity (mean 4096, sigma ~64)

// ---------------------------------------------------------------------------
// Kernel 1: h = sigmoid(x @ W_gate + b) * (x @ W).  W read from global (L1/L2
// hot, 512B contiguous per wave) -> no 64KB LDS stage, no bank conflicts.
// ---------------------------------------------------------------------------
__global__ __launch_bounds__(256) void fused_gemm_gate(
    const float* __restrict__ x, const float* __restrict__ W,
    const float* __restrict__ Wg, const float* __restrict__ bg,
    float* __restrict__ h, int n_nodes)
{
    __shared__ float Xt[D * BMP];   // X tile transposed [k][n], 33.3 KB
    __shared__ float Gs[BM];

    const int t = threadIdx.x;
    const int node0 = blockIdx.x * BM;

    // stage X tile transposed (coalesced global reads)
    for (int i = t; i < BM * (D / 4); i += 256) {
        int n  = i >> 5;          // 32 quads per node
        int kq = i & 31;
        int node = node0 + n;
        float4 v = make_float4(0.f, 0.f, 0.f, 0.f);
        if (node < n_nodes) v = *(const float4*)(x + (size_t)node * D + kq * 4);
        Xt[(kq * 4 + 0) * BMP + n] = v.x;
        Xt[(kq * 4 + 1) * BMP + n] = v.y;
        Xt[(kq * 4 + 2) * BMP + n] = v.z;
        Xt[(kq * 4 + 3) * BMP + n] = v.w;
    }
    __syncthreads();

    if (t < BM) {   // gates (conflict-free: bank = (k*65+t)%32 covers all banks)
        float gp = 0.f;
        #pragma unroll 8
        for (int k = 0; k < D; ++k) gp += Xt[k * BMP + t] * Wg[k];
        Gs[t] = 1.f / (1.f + __expf(-(gp + bg[0])));
    }
    __syncthreads();

    const int tf = t & 15;
    const int tn = t >> 4;
    const int f0 = tf * 8;
    const int n0 = tn * 4;

    float acc[4][8];
    #pragma unroll
    for (int i = 0; i < 4; ++i)
        #pragma unroll
        for (int j = 0; j < 8; ++j) acc[i][j] = 0.f;

    #pragma unroll 4
    for (int k = 0; k < D; ++k) {
        float4 xv = *(const float4*)&Xt[k * BMP + n0];             // broadcast
        float4 wa = *(const float4*)(W + (size_t)k * D + f0);      // global, 512B/wave
        float4 wb = *(const float4*)(W + (size_t)k * D + f0 + 4);
        float xr[4] = {xv.x, xv.y, xv.z, xv.w};
        float wr[8] = {wa.x, wa.y, wa.z, wa.w, wb.x, wb.y, wb.z, wb.w};
        #pragma unroll
        for (int i = 0; i < 4; ++i)
            #pragma unroll
            for (int j = 0; j < 8; ++j)
                acc[i][j] += xr[i] * wr[j];
    }

    #pragma unroll
    for (int i = 0; i < 4; ++i) {
        int node = node0 + n0 + i;
        if (node >= n_nodes) continue;
        float g = Gs[n0 + i];
        float4 o0 = make_float4(acc[i][0] * g, acc[i][1] * g, acc[i][2] * g, acc[i][3] * g);
        float4 o1 = make_float4(acc[i][4] * g, acc[i][5] * g, acc[i][6] * g, acc[i][7] * g);
        float* hp = h + (size_t)node * D + f0;
        *(float4*)(hp)     = o0;
        *(float4*)(hp + 4) = o1;
    }
}

// ---------------------------------------------------------------------------
// Row histogram + 2-level exclusive scan -> start[]
// ---------------------------------------------------------------------------
__global__ __launch_bounds__(256) void hist_rows(
    const int* __restrict__ er, int* __restrict__ cnt, int n_edges)
{
    int e = blockIdx.x * 256 + threadIdx.x;
    if (e < n_edges) atomicAdd(&cnt[er[e]], 1);
}

__global__ __launch_bounds__(256) void scan_pass1(
    const int* __restrict__ cnt, int* __restrict__ partials, int n)
{
    __shared__ int red[256];
    int t = threadIdx.x;
    int base = blockIdx.x * 1024 + t * 4;
    int s = 0;
    #pragma unroll
    for (int j = 0; j < 4; ++j)
        if (base + j < n) s += cnt[base + j];
    red[t] = s;
    __syncthreads();
    for (int off = 128; off > 0; off >>= 1) {
        if (t < off) red[t] += red[t + off];
        __syncthreads();
    }
    if (t == 0) partials[blockIdx.x] = red[0];
}

__global__ void scan_pass2(int* __restrict__ partials, int nblk)
{
    if (blockIdx.x == 0 && threadIdx.x == 0) {
        int run = 0;
        for (int i = 0; i < nblk; ++i) {
            int v = partials[i];
            partials[i] = run;
            run += v;
        }
    }
}

__global__ __launch_bounds__(256) void scan_pass3(
    const int* __restrict__ cnt, const int* __restrict__ partials,
    int* __restrict__ start, int n, int n_edges)
{
    __shared__ int wtot[4];
    int t = threadIdx.x;
    int lane = t & 63, w = t >> 6;
    int base = blockIdx.x * 1024 + t * 4;
    int v[4];
    int tsum = 0;
    #pragma unroll
    for (int j = 0; j < 4; ++j) {
        v[j] = (base + j < n) ? cnt[base + j] : 0;
        tsum += v[j];
    }
    int x = tsum;
    #pragma unroll
    for (int d = 1; d < 64; d <<= 1) {
        int y = __shfl_up(x, d);
        if (lane >= d) x += y;
    }
    int pre = x - tsum;
    if (lane == 63) wtot[w] = x;
    __syncthreads();
    int woff = 0;
    for (int i = 0; i < w; ++i) woff += wtot[i];
    int run = partials[blockIdx.x] + woff + pre;
    #pragma unroll
    for (int j = 0; j < 4; ++j) {
        if (base + j < n) {
            start[base + j] = run;
            run += v[j];
        }
    }
    if (blockIdx.x == 0 && t == 0) start[n] = n_edges;
}

// ---------------------------------------------------------------------------
// Pass A: bin edges into 256-row buckets via LDS staging.
// Entry format: {packed = col | (row&255)<<17, val_bits}. col<2^17 ok (N=100k).
// ---------------------------------------------------------------------------
__global__ __launch_bounds__(256) void bin_pass(
    const int* __restrict__ er, const int* __restrict__ ec,
    const float* __restrict__ ev, const int* __restrict__ start,
    int* __restrict__ gcursor, uint2* __restrict__ bucketArr,
    int n_edges, int nbkt)
{
    __shared__ uint2 staged[CHUNK];            // 32 KB
    __shared__ unsigned short bkt_of[CHUNK];   // 8 KB
    __shared__ int lcnt[NBKT_PAD];
    __shared__ int lbase[NBKT_PAD];
    __shared__ int gbase[NBKT_PAD];
    __shared__ int wt[4];

    const int t = threadIdx.x;
    const int lane = t & 63, w = t >> 6;
    const int e0 = blockIdx.x * CHUNK;
    const int ecnt = min(CHUNK, n_edges - e0);

    for (int i = t; i < NBKT_PAD; i += 256) lcnt[i] = 0;
    __syncthreads();

    // count buckets
    for (int i = t; i < ecnt; i += 256) atomicAdd(&lcnt[er[e0 + i] >> 8], 1);
    __syncthreads();

    // exclusive scan of 512 counters (2 per thread)
    {
        int a  = lcnt[2 * t];
        int b2 = lcnt[2 * t + 1];
        int tsum = a + b2;
        int x = tsum;
        #pragma unroll
        for (int d = 1; d < 64; d <<= 1) {
            int y = __shfl_up(x, d);
            if (lane >= d) x += y;
        }
        if (lane == 63) wt[w] = x;
        __syncthreads();
        int woff = 0;
        for (int i = 0; i < w; ++i) woff += wt[i];
        int pre = woff + x - tsum;
        lbase[2 * t]     = pre;
        lbase[2 * t + 1] = pre + a;
        lcnt[2 * t] = 0;          // reuse as fill cursor
        lcnt[2 * t + 1] = 0;
    }
    __syncthreads();

    // scatter into LDS, bucket-grouped
    for (int i = t; i < ecnt; i += 256) {
        int r = er[e0 + i];
        int b = r >> 8;
        int p = lbase[b] + atomicAdd(&lcnt[b], 1);
        staged[p] = make_uint2((unsigned)ec[e0 + i] | ((unsigned)(r & 255) << 17),
                               (unsigned)__float_as_int(ev[e0 + i]));
        bkt_of[p] = (unsigned short)b;
    }
    __syncthreads();

    // reserve global space per bucket (bucket base = start[b<<8])
    for (int i = t; i < nbkt; i += 256)
        gbase[i] = start[i << 8] + atomicAdd(&gcursor[i], lcnt[i]);
    __syncthreads();

    // bulk copy: contiguous LDS runs -> per-bucket global regions
    for (int i = t; i < ecnt; i += 256) {
        int b = bkt_of[i];
        bucketArr[gbase[b] + (i - lbase[b])] = staged[i];
    }
}

// ---------------------------------------------------------------------------
// Pass B: fine counting-sort of each bucket (256 rows) fully inside LDS.
// In-place on bucketArr: full segment read -> barrier -> scatter-write.
// ---------------------------------------------------------------------------
__global__ __launch_bounds__(256) void fine_sort(
    const int* __restrict__ start, uint2* __restrict__ bucketArr,
    int* __restrict__ ovf, int n_nodes)
{
    __shared__ uint2 inStg[BKT_CAP];   // 48 KB
    __shared__ int rcnt[256];
    __shared__ int rbase[256];
    __shared__ int wt[4];

    const int t = threadIdx.x;
    const int lane = t & 63, w = t >> 6;
    const int b = blockIdx.x;
    const int r0 = b << 8;
    const int r1 = min(r0 + 256, n_nodes);
    const int s = start[r0];
    const int e = start[r1];
    const int cnt = e - s;
    if (cnt == 0) return;

    if (cnt > BKT_CAP) {              // statistically impossible; flag for gather
        if (t == 0) ovf[b] = 1;
        return;
    }

    for (int i = t; i < cnt; i += 256) inStg[i] = bucketArr[s + i];
    rcnt[t] = 0;
    __syncthreads();

    for (int i = t; i < cnt; i += 256)
        atomicAdd(&rcnt[(inStg[i].x >> 17) & 255], 1);
    __syncthreads();

    // exclusive scan of 256 row counts
    {
        int v = rcnt[t];
        int x = v;
        #pragma unroll
        for (int d = 1; d < 64; d <<= 1) {
            int y = __shfl_up(x, d);
            if (lane >= d) x += y;
        }
        if (lane == 63) wt[w] = x;
        __syncthreads();
        int woff = 0;
        for (int i = 0; i < w; ++i) woff += wt[i];
        rbase[t] = woff + x - v;
    }
    __syncthreads();
    rcnt[t] = 0;
    __syncthreads();

    // scatter directly to global (8B stores into the 48KB L2-hot segment)
    for (int i = t; i < cnt; i += 256) {
        uint2 pe = inStg[i];
        int rl = (pe.x >> 17) & 255;
        int p  = rbase[rl] + atomicAdd(&rcnt[rl], 1);
        bucketArr[s + p] = pe;
    }
}

// ---------------------------------------------------------------------------
// Gather-reduce: one wave per row; lane l owns feats {2l, 2l+1}.
// ---------------------------------------------------------------------------
__global__ __launch_bounds__(256) void gather_rows(
    const int* __restrict__ start, const uint2* __restrict__ sorted,
    const int* __restrict__ ovf, const float* __restrict__ h,
    float* __restrict__ out, int n_nodes)
{
    int row  = (blockIdx.x * 256 + threadIdx.x) >> 6;
    int lane = threadIdx.x & 63;
    if (row >= n_nodes) return;

    int b = row >> 8;
    int s, e;
    bool filter = ovf[b] != 0;
    if (!filter) { s = start[row]; e = start[row + 1]; }
    else { s = start[b << 8]; e = start[min((b + 1) << 8, n_nodes)]; }
    unsigned target = (unsigned)(row & 255);

    float2 acc = make_float2(0.f, 0.f);
    for (int base = s; base < e; base += 64) {
        int idx = base + lane;
        uint2 pk = (idx < e) ? sorted[idx] : make_uint2(0u, 0u);
        int m = e - base; if (m > 64) m = 64;
        for (int j = 0; j < m; ++j) {
            unsigned px = (unsigned)__shfl((int)pk.x, j);
            float v     = __int_as_float(__shfl((int)pk.y, j));
            if (filter && ((px >> 17) & 255) != target) continue;
            int col = (int)(px & 0x1FFFFu);
            const float2 hv = *(const float2*)(h + (size_t)col * D + lane * 2);
            acc.x += v * hv.x;
            acc.y += v * hv.y;
        }
    }
    *(float2*)(out + (size_t)row * D + lane * 2) = acc;
}

// ---------------------------------------------------------------------------
// Fallback (ws too small): atomic scatter as in R1
// ---------------------------------------------------------------------------
__global__ __launch_bounds__(256) void scatter_edges(
    const int* __restrict__ er, const int* __restrict__ ec,
    const float* __restrict__ ev, const float* __restrict__ h,
    float* __restrict__ out, int n_edges)
{
    int gw   = (blockIdx.x * 256 + threadIdx.x) >> 6;
    int lane = threadIdx.x & 63;
    if (gw >= n_edges) return;
    int r = er[gw];
    int c = ec[gw];
    float v = ev[gw];
    const float2 hv = *(const float2*)(h + (size_t)c * D + lane * 2);
    float* op = out + (size_t)r * D + lane * 2;
    atomicAdd(op,     v * hv.x);
    atomicAdd(op + 1, v * hv.y);
}

extern "C" void kernel_launch(void* const* d_in, const int* in_sizes, int n_in,
                              void* d_out, int out_size, void* d_ws, size_t ws_size,
                              hipStream_t stream) {
    const float* x  = (const float*)d_in[0];
    const int*   er = (const int*)d_in[1];
    const int*   ec = (const int*)d_in[2];
    const float* ev = (const float*)d_in[3];
    const float* W  = (const float*)d_in[4];
    const float* Wg = (const float*)d_in[5];
    const float* bg = (const float*)d_in[6];
    float* out = (float*)d_out;

    const int n_nodes = in_sizes[0] / D;
    const int n_edges = in_sizes[1];
    const int nbkt = (n_nodes + 255) >> 8;

    // workspace layout
    char* ws = (char*)d_ws;
    size_t off = 0;
    auto alloc = [&](size_t bytes) {
        char* p = ws + off;
        off += (bytes + 15) & ~size_t(15);
        return p;
    };
    float* h        = (float*)alloc((size_t)n_nodes * D * sizeof(float));
    uint2* sorted   = (uint2*)alloc((size_t)n_edges * sizeof(uint2));   // bucketArr, sorted in place
    int*   startArr = (int*)  alloc((size_t)(n_nodes + 1) * sizeof(int));
    int*   cnt      = (int*)  alloc((size_t)n_nodes * sizeof(int));     // | contiguous
    int*   gcursor  = (int*)  alloc(NBKT_PAD * sizeof(int));            // | one
    int*   ovf      = (int*)  alloc(NBKT_PAD * sizeof(int));            // | memset
    int*   partials = (int*)  alloc(128 * sizeof(int));
    bool have_ws = off <= ws_size;

    // h = gate(x) * (x @ W)
    dim3 gemm_grid((n_nodes + BM - 1) / BM);
    fused_gemm_gate<<<gemm_grid, 256, 0, stream>>>(x, W, Wg, bg, h, n_nodes);

    if (have_ws) {
        size_t zbytes = (size_t)n_nodes * sizeof(int) + 2 * NBKT_PAD * sizeof(int);
        hipMemsetAsync(cnt, 0, zbytes, stream);
        int eb = (n_edges + 255) / 256;
        hist_rows<<<eb, 256, 0, stream>>>(er, cnt, n_edges);
        int nblk = (n_nodes + 1023) / 1024;
        scan_pass1<<<nblk, 256, 0, stream>>>(cnt, partials, n_nodes);
        scan_pass2<<<1, 64, 0, stream>>>(partials, nblk);
        scan_pass3<<<nblk, 256, 0, stream>>>(cnt, partials, startArr, n_nodes, n_edges);
        int cb = (n_edges + CHUNK - 1) / CHUNK;
        bin_pass<<<cb, 256, 0, stream>>>(er, ec, ev, startArr, gcursor, sorted, n_edges, nbkt);
        fine_sort<<<nbkt, 256, 0, stream>>>(startArr, sorted, ovf, n_nodes);
        int rb = (n_nodes * 64 + 255) / 256;
        gather_rows<<<rb, 256, 0, stream>>>(startArr, sorted, ovf, h, out, n_nodes);
    } else {
        hipMemsetAsync(d_out, 0, (size_t)out_size * sizeof(float), stream);
        int blocks = (n_edges + 3) / 4;
        scatter_edges<<<blocks, 256, 0, stream>>>(er, ec, ev, h, out, n_edges);
    }
}

// Round 4
// 306.053 us; speedup vs baseline: 4.6453x; 1.0599x over previous
//
#include <hip/hip_runtime.h>
#include <hip/hip_bf16.h>

constexpr int D        = 128;   // feature dim = K = UNITS
constexpr int BM       = 64;    // nodes per block in GEMM
constexpr int BMP      = BM + 1;
constexpr int CHUNK    = 4096;  // edges per binning block
constexpr int NBKT_PAD = 512;   // padded bucket count (actual = ceil(N/256) = 391)
constexpr int BKT_CAP  = 6144;  // fine-sort LDS capacity (mean 4096, sigma ~64)

// ---------------------------------------------------------------------------
// Kernel 1: h = sigmoid(x @ W_gate + b) * (x @ W), stored as bf16.
// ---------------------------------------------------------------------------
__global__ __launch_bounds__(256) void fused_gemm_gate(
    const float* __restrict__ x, const float* __restrict__ W,
    const float* __restrict__ Wg, const float* __restrict__ bg,
    __hip_bfloat16* __restrict__ h, int n_nodes)
{
    __shared__ float Xt[D * BMP];   // X tile transposed [k][n], 33.3 KB
    __shared__ float Gs[BM];

    const int t = threadIdx.x;
    const int node0 = blockIdx.x * BM;

    for (int i = t; i < BM * (D / 4); i += 256) {
        int n  = i >> 5;
        int kq = i & 31;
        int node = node0 + n;
        float4 v = make_float4(0.f, 0.f, 0.f, 0.f);
        if (node < n_nodes) v = *(const float4*)(x + (size_t)node * D + kq * 4);
        Xt[(kq * 4 + 0) * BMP + n] = v.x;
        Xt[(kq * 4 + 1) * BMP + n] = v.y;
        Xt[(kq * 4 + 2) * BMP + n] = v.z;
        Xt[(kq * 4 + 3) * BMP + n] = v.w;
    }
    __syncthreads();

    if (t < BM) {
        float gp = 0.f;
        #pragma unroll 8
        for (int k = 0; k < D; ++k) gp += Xt[k * BMP + t] * Wg[k];
        Gs[t] = 1.f / (1.f + __expf(-(gp + bg[0])));
    }
    __syncthreads();

    const int tf = t & 15;
    const int tn = t >> 4;
    const int f0 = tf * 8;
    const int n0 = tn * 4;

    float acc[4][8];
    #pragma unroll
    for (int i = 0; i < 4; ++i)
        #pragma unroll
        for (int j = 0; j < 8; ++j) acc[i][j] = 0.f;

    #pragma unroll 4
    for (int k = 0; k < D; ++k) {
        float4 xv = *(const float4*)&Xt[k * BMP + n0];
        float4 wa = *(const float4*)(W + (size_t)k * D + f0);
        float4 wb = *(const float4*)(W + (size_t)k * D + f0 + 4);
        float xr[4] = {xv.x, xv.y, xv.z, xv.w};
        float wr[8] = {wa.x, wa.y, wa.z, wa.w, wb.x, wb.y, wb.z, wb.w};
        #pragma unroll
        for (int i = 0; i < 4; ++i)
            #pragma unroll
            for (int j = 0; j < 8; ++j)
                acc[i][j] += xr[i] * wr[j];
    }

    #pragma unroll
    for (int i = 0; i < 4; ++i) {
        int node = node0 + n0 + i;
        if (node >= n_nodes) continue;
        float g = Gs[n0 + i];
        union { __hip_bfloat16 b[8]; int4 v; } u;
        #pragma unroll
        for (int j = 0; j < 8; ++j) u.b[j] = __float2bfloat16(acc[i][j] * g);
        *(int4*)(h + (size_t)node * D + f0) = u.v;
    }
}

// ---------------------------------------------------------------------------
// Row histogram + 2-level exclusive scan -> start[]
// ---------------------------------------------------------------------------
__global__ __launch_bounds__(256) void hist_rows(
    const int* __restrict__ er, int* __restrict__ cnt, int n_edges)
{
    int e = blockIdx.x * 256 + threadIdx.x;
    if (e < n_edges) atomicAdd(&cnt[er[e]], 1);
}

__global__ __launch_bounds__(256) void scan_pass1(
    const int* __restrict__ cnt, int* __restrict__ partials, int n)
{
    __shared__ int red[256];
    int t = threadIdx.x;
    int base = blockIdx.x * 1024 + t * 4;
    int s = 0;
    #pragma unroll
    for (int j = 0; j < 4; ++j)
        if (base + j < n) s += cnt[base + j];
    red[t] = s;
    __syncthreads();
    for (int off = 128; off > 0; off >>= 1) {
        if (t < off) red[t] += red[t + off];
        __syncthreads();
    }
    if (t == 0) partials[blockIdx.x] = red[0];
}

__global__ void scan_pass2(int* __restrict__ partials, int nblk)
{
    if (blockIdx.x == 0 && threadIdx.x == 0) {
        int run = 0;
        for (int i = 0; i < nblk; ++i) {
            int v = partials[i];
            partials[i] = run;
            run += v;
        }
    }
}

__global__ __launch_bounds__(256) void scan_pass3(
    const int* __restrict__ cnt, const int* __restrict__ partials,
    int* __restrict__ start, int n, int n_edges)
{
    __shared__ int wtot[4];
    int t = threadIdx.x;
    int lane = t & 63, w = t >> 6;
    int base = blockIdx.x * 1024 + t * 4;
    int v[4];
    int tsum = 0;
    #pragma unroll
    for (int j = 0; j < 4; ++j) {
        v[j] = (base + j < n) ? cnt[base + j] : 0;
        tsum += v[j];
    }
    int x = tsum;
    #pragma unroll
    for (int d = 1; d < 64; d <<= 1) {
        int y = __shfl_up(x, d);
        if (lane >= d) x += y;
    }
    int pre = x - tsum;
    if (lane == 63) wtot[w] = x;
    __syncthreads();
    int woff = 0;
    for (int i = 0; i < w; ++i) woff += wtot[i];
    int run = partials[blockIdx.x] + woff + pre;
    #pragma unroll
    for (int j = 0; j < 4; ++j) {
        if (base + j < n) {
            start[base + j] = run;
            run += v[j];
        }
    }
    if (blockIdx.x == 0 && t == 0) start[n] = n_edges;
}

// ---------------------------------------------------------------------------
// Pass A: bin edges into 256-row buckets via LDS staging.
// Entry: {packed = col | (row&255)<<17, val_bits}. col < 2^17 (N=100k).
// ---------------------------------------------------------------------------
__global__ __launch_bounds__(256) void bin_pass(
    const int* __restrict__ er, const int* __restrict__ ec,
    const float* __restrict__ ev, const int* __restrict__ start,
    int* __restrict__ gcursor, uint2* __restrict__ bucketArr,
    int n_edges, int nbkt)
{
    __shared__ uint2 staged[CHUNK];            // 32 KB
    __shared__ unsigned short bkt_of[CHUNK];   // 8 KB
    __shared__ int lcnt[NBKT_PAD];
    __shared__ int lbase[NBKT_PAD];
    __shared__ int gbase[NBKT_PAD];
    __shared__ int wt[4];

    const int t = threadIdx.x;
    const int lane = t & 63, w = t >> 6;
    const int e0 = blockIdx.x * CHUNK;
    const int ecnt = min(CHUNK, n_edges - e0);

    for (int i = t; i < NBKT_PAD; i += 256) lcnt[i] = 0;
    __syncthreads();

    for (int i = t; i < ecnt; i += 256) atomicAdd(&lcnt[er[e0 + i] >> 8], 1);
    __syncthreads();

    {   // exclusive scan of 512 counters (2 per thread)
        int a  = lcnt[2 * t];
        int b2 = lcnt[2 * t + 1];
        int tsum = a + b2;
        int x = tsum;
        #pragma unroll
        for (int d = 1; d < 64; d <<= 1) {
            int y = __shfl_up(x, d);
            if (lane >= d) x += y;
        }
        if (lane == 63) wt[w] = x;
        __syncthreads();
        int woff = 0;
        for (int i = 0; i < w; ++i) woff += wt[i];
        int pre = woff + x - tsum;
        lbase[2 * t]     = pre;
        lbase[2 * t + 1] = pre + a;
        lcnt[2 * t] = 0;
        lcnt[2 * t + 1] = 0;
    }
    __syncthreads();

    for (int i = t; i < ecnt; i += 256) {
        int r = er[e0 + i];
        int b = r >> 8;
        int p = lbase[b] + atomicAdd(&lcnt[b], 1);
        staged[p] = make_uint2((unsigned)ec[e0 + i] | ((unsigned)(r & 255) << 17),
                               (unsigned)__float_as_int(ev[e0 + i]));
        bkt_of[p] = (unsigned short)b;
    }
    __syncthreads();

    for (int i = t; i < nbkt; i += 256)
        gbase[i] = start[i << 8] + atomicAdd(&gcursor[i], lcnt[i]);
    __syncthreads();

    for (int i = t; i < ecnt; i += 256) {
        int b = bkt_of[i];
        bucketArr[gbase[b] + (i - lbase[b])] = staged[i];
    }
}

// ---------------------------------------------------------------------------
// Pass B: fine counting-sort of each bucket (256 rows) fully inside LDS.
// ---------------------------------------------------------------------------
__global__ __launch_bounds__(256) void fine_sort(
    const int* __restrict__ start, uint2* __restrict__ bucketArr,
    int* __restrict__ ovf, int n_nodes)
{
    __shared__ uint2 inStg[BKT_CAP];   // 48 KB
    __shared__ int rcnt[256];
    __shared__ int rbase[256];
    __shared__ int wt[4];

    const int t = threadIdx.x;
    const int lane = t & 63, w = t >> 6;
    const int b = blockIdx.x;
    const int r0 = b << 8;
    const int r1 = min(r0 + 256, n_nodes);
    const int s = start[r0];
    const int e = start[r1];
    const int cnt = e - s;
    if (cnt == 0) return;

    if (cnt > BKT_CAP) {
        if (t == 0) ovf[b] = 1;
        return;
    }

    for (int i = t; i < cnt; i += 256) inStg[i] = bucketArr[s + i];
    rcnt[t] = 0;
    __syncthreads();

    for (int i = t; i < cnt; i += 256)
        atomicAdd(&rcnt[(inStg[i].x >> 17) & 255], 1);
    __syncthreads();

    {   // exclusive scan of 256 row counts
        int v = rcnt[t];
        int x = v;
        #pragma unroll
        for (int d = 1; d < 64; d <<= 1) {
            int y = __shfl_up(x, d);
            if (lane >= d) x += y;
        }
        if (lane == 63) wt[w] = x;
        __syncthreads();
        int woff = 0;
        for (int i = 0; i < w; ++i) woff += wt[i];
        rbase[t] = woff + x - v;
    }
    __syncthreads();
    rcnt[t] = 0;
    __syncthreads();

    for (int i = t; i < cnt; i += 256) {
        uint2 pe = inStg[i];
        int rl = (pe.x >> 17) & 255;
        int p  = rbase[rl] + atomicAdd(&rcnt[rl], 1);
        bucketArr[s + p] = pe;
    }
}

// ---------------------------------------------------------------------------
// Gather-reduce: one wave per row; lane l owns feats {2l, 2l+1}.
// Wave-uniform edge loop: (col,val) live in SGPRs, no shuffles.
// ---------------------------------------------------------------------------
__global__ __launch_bounds__(256) void gather_rows(
    const int* __restrict__ start, const uint2* __restrict__ sorted,
    const int* __restrict__ ovf, const __hip_bfloat16* __restrict__ h,
    float* __restrict__ out, int n_nodes)
{
    int row  = (blockIdx.x * 256 + threadIdx.x) >> 6;
    int lane = threadIdx.x & 63;
    if (row >= n_nodes) return;

    int b = row >> 8;
    bool filter = ovf[b] != 0;
    int s, e;
    if (!filter) { s = start[row]; e = start[row + 1]; }
    else { s = start[b << 8]; e = start[min((b + 1) << 8, n_nodes)]; }
    s = __builtin_amdgcn_readfirstlane(s);
    e = __builtin_amdgcn_readfirstlane(e);
    const unsigned target = (unsigned)(row & 255);

    float2 acc = make_float2(0.f, 0.f);
    for (int i = s; i < e; ++i) {
        uint2 pk = sorted[i];                         // wave-uniform address
        unsigned px = __builtin_amdgcn_readfirstlane(pk.x);
        float v = __uint_as_float(__builtin_amdgcn_readfirstlane(pk.y));
        if (filter && ((px >> 17) & 255) != target) continue;
        int col = (int)(px & 0x1FFFFu);
        unsigned hv = *(const unsigned*)(h + (size_t)col * D + lane * 2);
        acc.x += v * __uint_as_float(hv << 16);
        acc.y += v * __uint_as_float(hv & 0xFFFF0000u);
    }
    *(float2*)(out + (size_t)row * D + lane * 2) = acc;
}

// ---------------------------------------------------------------------------
// Fallback (ws too small): atomic scatter
// ---------------------------------------------------------------------------
__global__ __launch_bounds__(256) void scatter_edges(
    const int* __restrict__ er, const int* __restrict__ ec,
    const float* __restrict__ ev, const __hip_bfloat16* __restrict__ h,
    float* __restrict__ out, int n_edges)
{
    int gw   = (blockIdx.x * 256 + threadIdx.x) >> 6;
    int lane = threadIdx.x & 63;
    if (gw >= n_edges) return;
    int r = er[gw];
    int c = ec[gw];
    float v = ev[gw];
    unsigned hv = *(const unsigned*)(h + (size_t)c * D + lane * 2);
    float* op = out + (size_t)r * D + lane * 2;
    atomicAdd(op,     v * __uint_as_float(hv << 16));
    atomicAdd(op + 1, v * __uint_as_float(hv & 0xFFFF0000u));
}

extern "C" void kernel_launch(void* const* d_in, const int* in_sizes, int n_in,
                              void* d_out, int out_size, void* d_ws, size_t ws_size,
                              hipStream_t stream) {
    const float* x  = (const float*)d_in[0];
    const int*   er = (const int*)d_in[1];
    const int*   ec = (const int*)d_in[2];
    const float* ev = (const float*)d_in[3];
    const float* W  = (const float*)d_in[4];
    const float* Wg = (const float*)d_in[5];
    const float* bg = (const float*)d_in[6];
    float* out = (float*)d_out;

    const int n_nodes = in_sizes[0] / D;
    const int n_edges = in_sizes[1];
    const int nbkt = (n_nodes + 255) >> 8;

    char* ws = (char*)d_ws;
    size_t off = 0;
    auto alloc = [&](size_t bytes) {
        char* p = ws + off;
        off += (bytes + 15) & ~size_t(15);
        return p;
    };
    __hip_bfloat16* h = (__hip_bfloat16*)alloc((size_t)n_nodes * D * sizeof(__hip_bfloat16));
    uint2* sorted   = (uint2*)alloc((size_t)n_edges * sizeof(uint2));
    int*   startArr = (int*)  alloc((size_t)(n_nodes + 1) * sizeof(int));
    int*   cnt      = (int*)  alloc((size_t)n_nodes * sizeof(int));   // | contiguous
    int*   gcursor  = (int*)  alloc(NBKT_PAD * sizeof(int));          // | single
    int*   ovf      = (int*)  alloc(NBKT_PAD * sizeof(int));          // | memset
    int*   partials = (int*)  alloc(128 * sizeof(int));
    bool have_ws = off <= ws_size;

    dim3 gemm_grid((n_nodes + BM - 1) / BM);
    fused_gemm_gate<<<gemm_grid, 256, 0, stream>>>(x, W, Wg, bg, h, n_nodes);

    if (have_ws) {
        size_t zbytes = (size_t)n_nodes * sizeof(int) + 2 * NBKT_PAD * sizeof(int);
        hipMemsetAsync(cnt, 0, zbytes, stream);
        int eb = (n_edges + 255) / 256;
        hist_rows<<<eb, 256, 0, stream>>>(er, cnt, n_edges);
        int nblk = (n_nodes + 1023) / 1024;
        scan_pass1<<<nblk, 256, 0, stream>>>(cnt, partials, n_nodes);
        scan_pass2<<<1, 64, 0, stream>>>(partials, nblk);
        scan_pass3<<<nblk, 256, 0, stream>>>(cnt, partials, startArr, n_nodes, n_edges);
        int cb = (n_edges + CHUNK - 1) / CHUNK;
        bin_pass<<<cb, 256, 0, stream>>>(er, ec, ev, startArr, gcursor, sorted, n_edges, nbkt);
        fine_sort<<<nbkt, 256, 0, stream>>>(startArr, sorted, ovf, n_nodes);
        int rb = (n_nodes * 64 + 255) / 256;
        gather_rows<<<rb, 256, 0, stream>>>(startArr, sorted, ovf, h, out, n_nodes);
    } else {
        hipMemsetAsync(d_out, 0, (size_t)out_size * sizeof(float), stream);
        int blocks = (n_edges + 3) / 4;
        scatter_edges<<<blocks, 256, 0, stream>>>(er, ec, ev, h, out, n_edges);
    }
}

// Round 5
// 263.741 us; speedup vs baseline: 5.3906x; 1.1604x over previous
//
#include <hip/hip_runtime.h>
#include <hip/hip_bf16.h>

constexpr int D        = 128;   // feature dim = K = UNITS
constexpr int BM       = 64;    // nodes per block in GEMM
constexpr int BMP      = BM + 1;
constexpr int CHUNK    = 4096;  // edges per binning block
constexpr int NBKT_PAD = 512;   // padded bucket count (actual = ceil(N/256) = 391)
constexpr int BKT_CAP  = 6144;  // fine-sort LDS capacity (mean 4096, sigma ~64)

// ---------------------------------------------------------------------------
// Kernel 1: h = sigmoid(x @ W_gate + b) * (x @ W), stored as bf16.
// ---------------------------------------------------------------------------
__global__ __launch_bounds__(256) void fused_gemm_gate(
    const float* __restrict__ x, const float* __restrict__ W,
    const float* __restrict__ Wg, const float* __restrict__ bg,
    __hip_bfloat16* __restrict__ h, int n_nodes)
{
    __shared__ float Xt[D * BMP];   // X tile transposed [k][n], 33.3 KB
    __shared__ float Gs[BM];

    const int t = threadIdx.x;
    const int node0 = blockIdx.x * BM;

    for (int i = t; i < BM * (D / 4); i += 256) {
        int n  = i >> 5;
        int kq = i & 31;
        int node = node0 + n;
        float4 v = make_float4(0.f, 0.f, 0.f, 0.f);
        if (node < n_nodes) v = *(const float4*)(x + (size_t)node * D + kq * 4);
        Xt[(kq * 4 + 0) * BMP + n] = v.x;
        Xt[(kq * 4 + 1) * BMP + n] = v.y;
        Xt[(kq * 4 + 2) * BMP + n] = v.z;
        Xt[(kq * 4 + 3) * BMP + n] = v.w;
    }
    __syncthreads();

    if (t < BM) {
        float gp = 0.f;
        #pragma unroll 8
        for (int k = 0; k < D; ++k) gp += Xt[k * BMP + t] * Wg[k];
        Gs[t] = 1.f / (1.f + __expf(-(gp + bg[0])));
    }
    __syncthreads();

    const int tf = t & 15;
    const int tn = t >> 4;
    const int f0 = tf * 8;
    const int n0 = tn * 4;

    float acc[4][8];
    #pragma unroll
    for (int i = 0; i < 4; ++i)
        #pragma unroll
        for (int j = 0; j < 8; ++j) acc[i][j] = 0.f;

    #pragma unroll 4
    for (int k = 0; k < D; ++k) {
        float4 xv = *(const float4*)&Xt[k * BMP + n0];
        float4 wa = *(const float4*)(W + (size_t)k * D + f0);
        float4 wb = *(const float4*)(W + (size_t)k * D + f0 + 4);
        float xr[4] = {xv.x, xv.y, xv.z, xv.w};
        float wr[8] = {wa.x, wa.y, wa.z, wa.w, wb.x, wb.y, wb.z, wb.w};
        #pragma unroll
        for (int i = 0; i < 4; ++i)
            #pragma unroll
            for (int j = 0; j < 8; ++j)
                acc[i][j] += xr[i] * wr[j];
    }

    #pragma unroll
    for (int i = 0; i < 4; ++i) {
        int node = node0 + n0 + i;
        if (node >= n_nodes) continue;
        float g = Gs[n0 + i];
        union { __hip_bfloat16 b[8]; int4 v; } u;
        #pragma unroll
        for (int j = 0; j < 8; ++j) u.b[j] = __float2bfloat16(acc[i][j] * g);
        *(int4*)(h + (size_t)node * D + f0) = u.v;
    }
}

// ---------------------------------------------------------------------------
// Row histogram + 2-level exclusive scan -> start[]
// ---------------------------------------------------------------------------
__global__ __launch_bounds__(256) void hist_rows(
    const int* __restrict__ er, int* __restrict__ cnt, int n_edges)
{
    int e = blockIdx.x * 256 + threadIdx.x;
    if (e < n_edges) atomicAdd(&cnt[er[e]], 1);
}

__global__ __launch_bounds__(256) void scan_pass1(
    const int* __restrict__ cnt, int* __restrict__ partials, int n)
{
    __shared__ int red[256];
    int t = threadIdx.x;
    int base = blockIdx.x * 1024 + t * 4;
    int s = 0;
    #pragma unroll
    for (int j = 0; j < 4; ++j)
        if (base + j < n) s += cnt[base + j];
    red[t] = s;
    __syncthreads();
    for (int off = 128; off > 0; off >>= 1) {
        if (t < off) red[t] += red[t + off];
        __syncthreads();
    }
    if (t == 0) partials[blockIdx.x] = red[0];
}

__global__ void scan_pass2(int* __restrict__ partials, int nblk)
{
    if (blockIdx.x == 0 && threadIdx.x == 0) {
        int run = 0;
        for (int i = 0; i < nblk; ++i) {
            int v = partials[i];
            partials[i] = run;
            run += v;
        }
    }
}

__global__ __launch_bounds__(256) void scan_pass3(
    const int* __restrict__ cnt, const int* __restrict__ partials,
    int* __restrict__ start, int n, int n_edges)
{
    __shared__ int wtot[4];
    int t = threadIdx.x;
    int lane = t & 63, w = t >> 6;
    int base = blockIdx.x * 1024 + t * 4;
    int v[4];
    int tsum = 0;
    #pragma unroll
    for (int j = 0; j < 4; ++j) {
        v[j] = (base + j < n) ? cnt[base + j] : 0;
        tsum += v[j];
    }
    int x = tsum;
    #pragma unroll
    for (int d = 1; d < 64; d <<= 1) {
        int y = __shfl_up(x, d);
        if (lane >= d) x += y;
    }
    int pre = x - tsum;
    if (lane == 63) wtot[w] = x;
    __syncthreads();
    int woff = 0;
    for (int i = 0; i < w; ++i) woff += wtot[i];
    int run = partials[blockIdx.x] + woff + pre;
    #pragma unroll
    for (int j = 0; j < 4; ++j) {
        if (base + j < n) {
            start[base + j] = run;
            run += v[j];
        }
    }
    if (blockIdx.x == 0 && t == 0) start[n] = n_edges;
}

// ---------------------------------------------------------------------------
// Pass A: bin edges into 256-row buckets via LDS staging.
// Entry: {packed = col | (row&255)<<17, val_bits}. col < 2^17 (N=100k).
// ---------------------------------------------------------------------------
__global__ __launch_bounds__(256) void bin_pass(
    const int* __restrict__ er, const int* __restrict__ ec,
    const float* __restrict__ ev, const int* __restrict__ start,
    int* __restrict__ gcursor, uint2* __restrict__ bucketArr,
    int n_edges, int nbkt)
{
    __shared__ uint2 staged[CHUNK];            // 32 KB
    __shared__ unsigned short bkt_of[CHUNK];   // 8 KB
    __shared__ int lcnt[NBKT_PAD];
    __shared__ int lbase[NBKT_PAD];
    __shared__ int gbase[NBKT_PAD];
    __shared__ int wt[4];

    const int t = threadIdx.x;
    const int lane = t & 63, w = t >> 6;
    const int e0 = blockIdx.x * CHUNK;
    const int ecnt = min(CHUNK, n_edges - e0);

    for (int i = t; i < NBKT_PAD; i += 256) lcnt[i] = 0;
    __syncthreads();

    for (int i = t; i < ecnt; i += 256) atomicAdd(&lcnt[er[e0 + i] >> 8], 1);
    __syncthreads();

    {   // exclusive scan of 512 counters (2 per thread)
        int a  = lcnt[2 * t];
        int b2 = lcnt[2 * t + 1];
        int tsum = a + b2;
        int x = tsum;
        #pragma unroll
        for (int d = 1; d < 64; d <<= 1) {
            int y = __shfl_up(x, d);
            if (lane >= d) x += y;
        }
        if (lane == 63) wt[w] = x;
        __syncthreads();
        int woff = 0;
        for (int i = 0; i < w; ++i) woff += wt[i];
        int pre = woff + x - tsum;
        lbase[2 * t]     = pre;
        lbase[2 * t + 1] = pre + a;
        lcnt[2 * t] = 0;
        lcnt[2 * t + 1] = 0;
    }
    __syncthreads();

    for (int i = t; i < ecnt; i += 256) {
        int r = er[e0 + i];
        int b = r >> 8;
        int p = lbase[b] + atomicAdd(&lcnt[b], 1);
        staged[p] = make_uint2((unsigned)ec[e0 + i] | ((unsigned)(r & 255) << 17),
                               (unsigned)__float_as_int(ev[e0 + i]));
        bkt_of[p] = (unsigned short)b;
    }
    __syncthreads();

    for (int i = t; i < nbkt; i += 256)
        gbase[i] = start[i << 8] + atomicAdd(&gcursor[i], lcnt[i]);
    __syncthreads();

    for (int i = t; i < ecnt; i += 256) {
        int b = bkt_of[i];
        bucketArr[gbase[b] + (i - lbase[b])] = staged[i];
    }
}

// ---------------------------------------------------------------------------
// Pass B: fine counting-sort of each bucket (256 rows) fully inside LDS.
// ---------------------------------------------------------------------------
__global__ __launch_bounds__(256) void fine_sort(
    const int* __restrict__ start, uint2* __restrict__ bucketArr,
    int* __restrict__ ovf, int n_nodes)
{
    __shared__ uint2 inStg[BKT_CAP];   // 48 KB
    __shared__ int rcnt[256];
    __shared__ int rbase[256];
    __shared__ int wt[4];

    const int t = threadIdx.x;
    const int lane = t & 63, w = t >> 6;
    const int b = blockIdx.x;
    const int r0 = b << 8;
    const int r1 = min(r0 + 256, n_nodes);
    const int s = start[r0];
    const int e = start[r1];
    const int cnt = e - s;
    if (cnt == 0) return;

    if (cnt > BKT_CAP) {
        if (t == 0) ovf[b] = 1;
        return;
    }

    for (int i = t; i < cnt; i += 256) inStg[i] = bucketArr[s + i];
    rcnt[t] = 0;
    __syncthreads();

    for (int i = t; i < cnt; i += 256)
        atomicAdd(&rcnt[(inStg[i].x >> 17) & 255], 1);
    __syncthreads();

    {   // exclusive scan of 256 row counts
        int v = rcnt[t];
        int x = v;
        #pragma unroll
        for (int d = 1; d < 64; d <<= 1) {
            int y = __shfl_up(x, d);
            if (lane >= d) x += y;
        }
        if (lane == 63) wt[w] = x;
        __syncthreads();
        int woff = 0;
        for (int i = 0; i < w; ++i) woff += wt[i];
        rbase[t] = woff + x - v;
    }
    __syncthreads();
    rcnt[t] = 0;
    __syncthreads();

    for (int i = t; i < cnt; i += 256) {
        uint2 pe = inStg[i];
        int rl = (pe.x >> 17) & 255;
        int p  = rbase[rl] + atomicAdd(&rcnt[rl], 1);
        bucketArr[s + p] = pe;
    }
}

// ---------------------------------------------------------------------------
// Gather-reduce: one wave per row, 4 edges in flight per wave.
// Lane = (g,p): group g=lane>>4 handles edge base+g; lane covers feats
// [p*8, p*8+8) via one dwordx4 (16B) bf16 load. Butterfly-reduce over g.
// ---------------------------------------------------------------------------
__global__ __launch_bounds__(256) void gather_rows(
    const int* __restrict__ start, const uint2* __restrict__ sorted,
    const int* __restrict__ ovf, const __hip_bfloat16* __restrict__ h,
    float* __restrict__ out, int n_nodes)
{
    int row  = (blockIdx.x * 256 + threadIdx.x) >> 6;
    int lane = threadIdx.x & 63;
    if (row >= n_nodes) return;

    int b = row >> 8;
    bool filter = ovf[b] != 0;
    int s, e;
    if (!filter) { s = start[row]; e = start[row + 1]; }
    else { s = start[b << 8]; e = start[min((b + 1) << 8, n_nodes)]; }

    const int g = lane >> 4;          // edge slot 0..3
    const int p = lane & 15;          // feat block (8 feats)
    const unsigned target = (unsigned)(row & 255);

    float acc[8];
    #pragma unroll
    for (int j = 0; j < 8; ++j) acc[j] = 0.f;

    for (int base = s; base < e; base += 4) {
        int idx = base + g;
        float v = 0.f;
        int col = 0;
        if (idx < e) {
            uint2 pk = sorted[idx];
            if (!filter || ((pk.x >> 17) & 255) == target) {
                v   = __uint_as_float(pk.y);
                col = (int)(pk.x & 0x1FFFFu);
            }
        }
        const int4 hv = *(const int4*)(h + (size_t)col * D + p * 8);
        unsigned d0 = (unsigned)hv.x, d1 = (unsigned)hv.y;
        unsigned d2 = (unsigned)hv.z, d3 = (unsigned)hv.w;
        acc[0] += v * __uint_as_float(d0 << 16);
        acc[1] += v * __uint_as_float(d0 & 0xFFFF0000u);
        acc[2] += v * __uint_as_float(d1 << 16);
        acc[3] += v * __uint_as_float(d1 & 0xFFFF0000u);
        acc[4] += v * __uint_as_float(d2 << 16);
        acc[5] += v * __uint_as_float(d2 & 0xFFFF0000u);
        acc[6] += v * __uint_as_float(d3 << 16);
        acc[7] += v * __uint_as_float(d3 & 0xFFFF0000u);
    }

    // reduce across the 4 edge slots (lane bits 4,5)
    #pragma unroll
    for (int j = 0; j < 8; ++j) {
        acc[j] += __shfl_xor(acc[j], 16);
        acc[j] += __shfl_xor(acc[j], 32);
    }

    if (lane < 16) {
        float* op = out + (size_t)row * D + lane * 8;
        *(float4*)(op)     = make_float4(acc[0], acc[1], acc[2], acc[3]);
        *(float4*)(op + 4) = make_float4(acc[4], acc[5], acc[6], acc[7]);
    }
}

// ---------------------------------------------------------------------------
// Fallback (ws too small): atomic scatter
// ---------------------------------------------------------------------------
__global__ __launch_bounds__(256) void scatter_edges(
    const int* __restrict__ er, const int* __restrict__ ec,
    const float* __restrict__ ev, const __hip_bfloat16* __restrict__ h,
    float* __restrict__ out, int n_edges)
{
    int gw   = (blockIdx.x * 256 + threadIdx.x) >> 6;
    int lane = threadIdx.x & 63;
    if (gw >= n_edges) return;
    int r = er[gw];
    int c = ec[gw];
    float v = ev[gw];
    unsigned hv = *(const unsigned*)(h + (size_t)c * D + lane * 2);
    float* op = out + (size_t)r * D + lane * 2;
    atomicAdd(op,     v * __uint_as_float(hv << 16));
    atomicAdd(op + 1, v * __uint_as_float(hv & 0xFFFF0000u));
}

extern "C" void kernel_launch(void* const* d_in, const int* in_sizes, int n_in,
                              void* d_out, int out_size, void* d_ws, size_t ws_size,
                              hipStream_t stream) {
    const float* x  = (const float*)d_in[0];
    const int*   er = (const int*)d_in[1];
    const int*   ec = (const int*)d_in[2];
    const float* ev = (const float*)d_in[3];
    const float* W  = (const float*)d_in[4];
    const float* Wg = (const float*)d_in[5];
    const float* bg = (const float*)d_in[6];
    float* out = (float*)d_out;

    const int n_nodes = in_sizes[0] / D;
    const int n_edges = in_sizes[1];
    const int nbkt = (n_nodes + 255) >> 8;

    char* ws = (char*)d_ws;
    size_t off = 0;
    auto alloc = [&](size_t bytes) {
        char* p = ws + off;
        off += (bytes + 15) & ~size_t(15);
        return p;
    };
    __hip_bfloat16* h = (__hip_bfloat16*)alloc((size_t)n_nodes * D * sizeof(__hip_bfloat16));
    uint2* sorted   = (uint2*)alloc((size_t)n_edges * sizeof(uint2));
    int*   startArr = (int*)  alloc((size_t)(n_nodes + 1) * sizeof(int));
    int*   cnt      = (int*)  alloc((size_t)n_nodes * sizeof(int));   // | contiguous
    int*   gcursor  = (int*)  alloc(NBKT_PAD * sizeof(int));          // | single
    int*   ovf      = (int*)  alloc(NBKT_PAD * sizeof(int));          // | memset
    int*   partials = (int*)  alloc(128 * sizeof(int));
    bool have_ws = off <= ws_size;

    dim3 gemm_grid((n_nodes + BM - 1) / BM);
    fused_gemm_gate<<<gemm_grid, 256, 0, stream>>>(x, W, Wg, bg, h, n_nodes);

    if (have_ws) {
        size_t zbytes = (size_t)n_nodes * sizeof(int) + 2 * NBKT_PAD * sizeof(int);
        hipMemsetAsync(cnt, 0, zbytes, stream);
        int eb = (n_edges + 255) / 256;
        hist_rows<<<eb, 256, 0, stream>>>(er, cnt, n_edges);
        int nblk = (n_nodes + 1023) / 1024;
        scan_pass1<<<nblk, 256, 0, stream>>>(cnt, partials, n_nodes);
        scan_pass2<<<1, 64, 0, stream>>>(partials, nblk);
        scan_pass3<<<nblk, 256, 0, stream>>>(cnt, partials, startArr, n_nodes, n_edges);
        int cb = (n_edges + CHUNK - 1) / CHUNK;
        bin_pass<<<cb, 256, 0, stream>>>(er, ec, ev, startArr, gcursor, sorted, n_edges, nbkt);
        fine_sort<<<nbkt, 256, 0, stream>>>(startArr, sorted, ovf, n_nodes);
        int rb = (n_nodes * 64 + 255) / 256;
        gather_rows<<<rb, 256, 0, stream>>>(startArr, sorted, ovf, h, out, n_nodes);
    } else {
        hipMemsetAsync(d_out, 0, (size_t)out_size * sizeof(float), stream);
        int blocks = (n_edges + 3) / 4;
        scatter_edges<<<blocks, 256, 0, stream>>>(er, ec, ev, h, out, n_edges);
    }
}

// Round 6
// 237.726 us; speedup vs baseline: 5.9805x; 1.1094x over previous
//
#include <hip/hip_runtime.h>
#include <hip/hip_bf16.h>

constexpr int D        = 128;   // feature dim = K = UNITS
constexpr int BM       = 64;    // nodes per block in GEMM
constexpr int CHUNK    = 4096;  // edges per binning block
constexpr int NBKT_PAD = 512;   // padded bucket count (actual = ceil(N/256) = 391)
constexpr int BKT_CAP  = 6144;  // fine-sort LDS capacity (mean 4096, sigma ~64)

typedef __attribute__((ext_vector_type(8))) short bf16x8;
typedef __attribute__((ext_vector_type(4))) float f32x4;

__device__ __forceinline__ unsigned short rne_bf16(float f) {
    unsigned u = __float_as_uint(f);
    return (unsigned short)((u + 0x7FFF + ((u >> 16) & 1)) >> 16);
}

// ---------------------------------------------------------------------------
// One-time: W[k][f] f32 -> Wt_sw (transposed [f][k] bf16, XOR-pre-swizzled so
// a LINEAR LDS copy yields swizzled layout; element idx = f*128 + (k ^ ((f&7)<<3)))
// ---------------------------------------------------------------------------
__global__ __launch_bounds__(256) void transpose_W(
    const float* __restrict__ W, unsigned short* __restrict__ wt_sw)
{
    int idx = blockIdx.x * 256 + threadIdx.x;   // 16384 elems
    int k = idx >> 7, f = idx & 127;
    wt_sw[f * 128 + (k ^ ((f & 7) << 3))] = rne_bf16(W[idx]);
}

// ---------------------------------------------------------------------------
// Kernel 1: h = sigmoid(x @ W_gate + b) * (x @ W) via bf16x2 MFMA, h bf16.
// Tile 64 nodes x 128 feats, K=128. 4 waves; wave w covers feats [w*32,w*32+32).
// ---------------------------------------------------------------------------
__global__ __launch_bounds__(256) void mfma_gemm_gate(
    const float* __restrict__ x, const unsigned short* __restrict__ wt_sw,
    const float* __restrict__ Wg, const float* __restrict__ bg,
    __hip_bfloat16* __restrict__ h, int n_nodes)
{
    __shared__ __align__(16) char smem[65792];
    unsigned short* Ahi = (unsigned short*)smem;           // [64][128] swz, 16KB
    unsigned short* Alo = Ahi + 64 * 128;                  // 16KB
    unsigned short* Bt  = Alo + 64 * 128;                  // [128][128] swz, 32KB
    float*          Gs  = (float*)(Bt + 128 * 128);        // [64]
    unsigned short* Cbuf = (unsigned short*)smem;          // [64][136] reuse, 17KB

    const int t    = threadIdx.x;
    const int lane = t & 63;
    const int w    = t >> 6;
    const int node0 = blockIdx.x * BM;

    // ---- stage W tile: linear copy of pre-swizzled source (conflict-free)
    #pragma unroll
    for (int i = 0; i < 8; ++i) {
        int e0 = (i * 256 + t) * 8;
        *(int4*)&Bt[e0] = *(const int4*)&wt_sw[e0];
    }

    // ---- stage x tile as bf16 hi/lo, XOR-swizzled
    #pragma unroll
    for (int i = 0; i < 8; ++i) {
        int fidx = (i * 256 + t) * 4;          // flat f32 index in 64x128 tile
        int row  = fidx >> 7;
        int k    = fidx & 127;
        int node = node0 + row;
        float4 v = make_float4(0.f, 0.f, 0.f, 0.f);
        if (node < n_nodes) v = *(const float4*)(x + (size_t)node * D + k);
        unsigned short hi[4], lo[4];
        float vf[4] = {v.x, v.y, v.z, v.w};
        #pragma unroll
        for (int j = 0; j < 4; ++j) {
            hi[j] = rne_bf16(vf[j]);
            float fh = __uint_as_float((unsigned)hi[j] << 16);
            lo[j] = rne_bf16(vf[j] - fh);
        }
        int eidx = row * 128 + (k ^ ((row & 7) << 3));
        *(unsigned long long*)&Ahi[eidx] =
            (unsigned long long)hi[0] | ((unsigned long long)hi[1] << 16) |
            ((unsigned long long)hi[2] << 32) | ((unsigned long long)hi[3] << 48);
        *(unsigned long long*)&Alo[eidx] =
            (unsigned long long)lo[0] | ((unsigned long long)lo[1] << 16) |
            ((unsigned long long)lo[2] << 32) | ((unsigned long long)lo[3] << 48);
    }
    __syncthreads();

    // ---- gate (wave 0): gp = dot(x_hi[row], Wg); Gs = sigmoid(gp + b)
    if (t < BM) {
        float gp = 0.f;
        #pragma unroll
        for (int kq = 0; kq < 16; ++kq) {
            int eidx = t * 128 + ((kq * 8) ^ ((t & 7) << 3));
            unsigned long long a = *(const unsigned long long*)&Ahi[eidx];
            unsigned long long b = *(const unsigned long long*)&Ahi[eidx + 4];
            #pragma unroll
            for (int j = 0; j < 4; ++j) {
                gp += __uint_as_float((unsigned)((a >> (16 * j)) & 0xFFFF) << 16) * Wg[kq * 8 + j];
                gp += __uint_as_float((unsigned)((b >> (16 * j)) & 0xFFFF) << 16) * Wg[kq * 8 + 4 + j];
            }
        }
        Gs[t] = 1.f / (1.f + __expf(-(gp + bg[0])));
    }

    // ---- MFMA main loop: acc[m][n] over K
    f32x4 acc[4][2];
    #pragma unroll
    for (int m = 0; m < 4; ++m)
        #pragma unroll
        for (int n = 0; n < 2; ++n)
            acc[m][n] = (f32x4){0.f, 0.f, 0.f, 0.f};

    #pragma unroll
    for (int kk = 0; kk < 4; ++kk) {
        const int k0 = kk * 32 + (lane >> 4) * 8;
        bf16x8 bfr[2];
        #pragma unroll
        for (int n = 0; n < 2; ++n) {
            int f = w * 32 + n * 16 + (lane & 15);
            bfr[n] = *(const bf16x8*)&Bt[f * 128 + (k0 ^ ((f & 7) << 3))];
        }
        #pragma unroll
        for (int m = 0; m < 4; ++m) {
            int row = m * 16 + (lane & 15);
            int eidx = row * 128 + (k0 ^ ((row & 7) << 3));
            bf16x8 ah = *(const bf16x8*)&Ahi[eidx];
            bf16x8 al = *(const bf16x8*)&Alo[eidx];
            #pragma unroll
            for (int n = 0; n < 2; ++n) {
                acc[m][n] = __builtin_amdgcn_mfma_f32_16x16x32_bf16(ah, bfr[n], acc[m][n], 0, 0, 0);
                acc[m][n] = __builtin_amdgcn_mfma_f32_16x16x32_bf16(al, bfr[n], acc[m][n], 0, 0, 0);
            }
        }
    }
    __syncthreads();   // A/B LDS dead; Gs ready

    // ---- epilogue: gate-scale, cvt bf16, scatter to Cbuf [64][136]
    #pragma unroll
    for (int m = 0; m < 4; ++m) {
        #pragma unroll
        for (int n = 0; n < 2; ++n) {
            int feat = w * 32 + n * 16 + (lane & 15);
            #pragma unroll
            for (int j = 0; j < 4; ++j) {
                int rloc = m * 16 + (lane >> 4) * 4 + j;
                Cbuf[rloc * 136 + feat] = rne_bf16(acc[m][n][j] * Gs[rloc]);
            }
        }
    }
    __syncthreads();

    // ---- coalesced store: thread t -> row t>>2, feats (t&3)*32..+32
    {
        int row  = t >> 2;
        int fb   = (t & 3) * 32;
        int node = node0 + row;
        if (node < n_nodes) {
            __hip_bfloat16* hp = h + (size_t)node * D + fb;
            #pragma unroll
            for (int q = 0; q < 4; ++q)
                *(int4*)(hp + q * 8) = *(const int4*)&Cbuf[row * 136 + fb + q * 8];
        }
    }
}

// ---------------------------------------------------------------------------
// Row histogram + 2-level exclusive scan -> start[]
// ---------------------------------------------------------------------------
__global__ __launch_bounds__(256) void hist_rows(
    const int* __restrict__ er, int* __restrict__ cnt, int n_edges)
{
    int e = blockIdx.x * 256 + threadIdx.x;
    if (e < n_edges) atomicAdd(&cnt[er[e]], 1);
}

__global__ __launch_bounds__(256) void scan_pass1(
    const int* __restrict__ cnt, int* __restrict__ partials, int n)
{
    __shared__ int red[256];
    int t = threadIdx.x;
    int base = blockIdx.x * 1024 + t * 4;
    int s = 0;
    #pragma unroll
    for (int j = 0; j < 4; ++j)
        if (base + j < n) s += cnt[base + j];
    red[t] = s;
    __syncthreads();
    for (int off = 128; off > 0; off >>= 1) {
        if (t < off) red[t] += red[t + off];
        __syncthreads();
    }
    if (t == 0) partials[blockIdx.x] = red[0];
}

__global__ void scan_pass2(int* __restrict__ partials, int nblk)
{
    if (blockIdx.x == 0 && threadIdx.x == 0) {
        int run = 0;
        for (int i = 0; i < nblk; ++i) {
            int v = partials[i];
            partials[i] = run;
            run += v;
        }
    }
}

__global__ __launch_bounds__(256) void scan_pass3(
    const int* __restrict__ cnt, const int* __restrict__ partials,
    int* __restrict__ start, int n, int n_edges)
{
    __shared__ int wtot[4];
    int t = threadIdx.x;
    int lane = t & 63, w = t >> 6;
    int base = blockIdx.x * 1024 + t * 4;
    int v[4];
    int tsum = 0;
    #pragma unroll
    for (int j = 0; j < 4; ++j) {
        v[j] = (base + j < n) ? cnt[base + j] : 0;
        tsum += v[j];
    }
    int x = tsum;
    #pragma unroll
    for (int d = 1; d < 64; d <<= 1) {
        int y = __shfl_up(x, d);
        if (lane >= d) x += y;
    }
    int pre = x - tsum;
    if (lane == 63) wtot[w] = x;
    __syncthreads();
    int woff = 0;
    for (int i = 0; i < w; ++i) woff += wtot[i];
    int run = partials[blockIdx.x] + woff + pre;
    #pragma unroll
    for (int j = 0; j < 4; ++j) {
        if (base + j < n) {
            start[base + j] = run;
            run += v[j];
        }
    }
    if (blockIdx.x == 0 && t == 0) start[n] = n_edges;
}

// ---------------------------------------------------------------------------
// Pass A: bin edges into 256-row buckets via LDS staging.
// Entry: {packed = col | (row&255)<<17, val_bits}. col < 2^17 (N=100k).
// ---------------------------------------------------------------------------
__global__ __launch_bounds__(256) void bin_pass(
    const int* __restrict__ er, const int* __restrict__ ec,
    const float* __restrict__ ev, const int* __restrict__ start,
    int* __restrict__ gcursor, uint2* __restrict__ bucketArr,
    int n_edges, int nbkt)
{
    __shared__ uint2 staged[CHUNK];            // 32 KB
    __shared__ unsigned short bkt_of[CHUNK];   // 8 KB
    __shared__ int lcnt[NBKT_PAD];
    __shared__ int lbase[NBKT_PAD];
    __shared__ int gbase[NBKT_PAD];
    __shared__ int wt[4];

    const int t = threadIdx.x;
    const int lane = t & 63, w = t >> 6;
    const int e0 = blockIdx.x * CHUNK;
    const int ecnt = min(CHUNK, n_edges - e0);

    for (int i = t; i < NBKT_PAD; i += 256) lcnt[i] = 0;
    __syncthreads();

    for (int i = t; i < ecnt; i += 256) atomicAdd(&lcnt[er[e0 + i] >> 8], 1);
    __syncthreads();

    {   // exclusive scan of 512 counters (2 per thread)
        int a  = lcnt[2 * t];
        int b2 = lcnt[2 * t + 1];
        int tsum = a + b2;
        int x = tsum;
        #pragma unroll
        for (int d = 1; d < 64; d <<= 1) {
            int y = __shfl_up(x, d);
            if (lane >= d) x += y;
        }
        if (lane == 63) wt[w] = x;
        __syncthreads();
        int woff = 0;
        for (int i = 0; i < w; ++i) woff += wt[i];
        int pre = woff + x - tsum;
        lbase[2 * t]     = pre;
        lbase[2 * t + 1] = pre + a;
        lcnt[2 * t] = 0;
        lcnt[2 * t + 1] = 0;
    }
    __syncthreads();

    for (int i = t; i < ecnt; i += 256) {
        int r = er[e0 + i];
        int b = r >> 8;
        int p = lbase[b] + atomicAdd(&lcnt[b], 1);
        staged[p] = make_uint2((unsigned)ec[e0 + i] | ((unsigned)(r & 255) << 17),
                               (unsigned)__float_as_int(ev[e0 + i]));
        bkt_of[p] = (unsigned short)b;
    }
    __syncthreads();

    for (int i = t; i < nbkt; i += 256)
        gbase[i] = start[i << 8] + atomicAdd(&gcursor[i], lcnt[i]);
    __syncthreads();

    for (int i = t; i < ecnt; i += 256) {
        int b = bkt_of[i];
        bucketArr[gbase[b] + (i - lbase[b])] = staged[i];
    }
}

// ---------------------------------------------------------------------------
// Pass B: fine counting-sort of each bucket (256 rows) fully inside LDS.
// ---------------------------------------------------------------------------
__global__ __launch_bounds__(256) void fine_sort(
    const int* __restrict__ start, uint2* __restrict__ bucketArr,
    int* __restrict__ ovf, int n_nodes)
{
    __shared__ uint2 inStg[BKT_CAP];   // 48 KB
    __shared__ int rcnt[256];
    __shared__ int rbase[256];
    __shared__ int wt[4];

    const int t = threadIdx.x;
    const int lane = t & 63, w = t >> 6;
    const int b = blockIdx.x;
    const int r0 = b << 8;
    const int r1 = min(r0 + 256, n_nodes);
    const int s = start[r0];
    const int e = start[r1];
    const int cnt = e - s;
    if (cnt == 0) return;

    if (cnt > BKT_CAP) {
        if (t == 0) ovf[b] = 1;
        return;
    }

    for (int i = t; i < cnt; i += 256) inStg[i] = bucketArr[s + i];
    rcnt[t] = 0;
    __syncthreads();

    for (int i = t; i < cnt; i += 256)
        atomicAdd(&rcnt[(inStg[i].x >> 17) & 255], 1);
    __syncthreads();

    {   // exclusive scan of 256 row counts
        int v = rcnt[t];
        int x = v;
        #pragma unroll
        for (int d = 1; d < 64; d <<= 1) {
            int y = __shfl_up(x, d);
            if (lane >= d) x += y;
        }
        if (lane == 63) wt[w] = x;
        __syncthreads();
        int woff = 0;
        for (int i = 0; i < w; ++i) woff += wt[i];
        rbase[t] = woff + x - v;
    }
    __syncthreads();
    rcnt[t] = 0;
    __syncthreads();

    for (int i = t; i < cnt; i += 256) {
        uint2 pe = inStg[i];
        int rl = (pe.x >> 17) & 255;
        int p  = rbase[rl] + atomicAdd(&rcnt[rl], 1);
        bucketArr[s + p] = pe;
    }
}

// ---------------------------------------------------------------------------
// Gather-reduce: one wave per row, 4 edges in flight per wave.
// ---------------------------------------------------------------------------
__global__ __launch_bounds__(256) void gather_rows(
    const int* __restrict__ start, const uint2* __restrict__ sorted,
    const int* __restrict__ ovf, const __hip_bfloat16* __restrict__ h,
    float* __restrict__ out, int n_nodes)
{
    int row  = (blockIdx.x * 256 + threadIdx.x) >> 6;
    int lane = threadIdx.x & 63;
    if (row >= n_nodes) return;

    int b = row >> 8;
    bool filter = ovf[b] != 0;
    int s, e;
    if (!filter) { s = start[row]; e = start[row + 1]; }
    else { s = start[b << 8]; e = start[min((b + 1) << 8, n_nodes)]; }

    const int g = lane >> 4;          // edge slot 0..3
    const int p = lane & 15;          // feat block (8 feats)
    const unsigned target = (unsigned)(row & 255);

    float acc[8];
    #pragma unroll
    for (int j = 0; j < 8; ++j) acc[j] = 0.f;

    for (int base = s; base < e; base += 4) {
        int idx = base + g;
        float v = 0.f;
        int col = 0;
        if (idx < e) {
            uint2 pk = sorted[idx];
            if (!filter || ((pk.x >> 17) & 255) == target) {
                v   = __uint_as_float(pk.y);
                col = (int)(pk.x & 0x1FFFFu);
            }
        }
        const int4 hv = *(const int4*)(h + (size_t)col * D + p * 8);
        unsigned d0 = (unsigned)hv.x, d1 = (unsigned)hv.y;
        unsigned d2 = (unsigned)hv.z, d3 = (unsigned)hv.w;
        acc[0] += v * __uint_as_float(d0 << 16);
        acc[1] += v * __uint_as_float(d0 & 0xFFFF0000u);
        acc[2] += v * __uint_as_float(d1 << 16);
        acc[3] += v * __uint_as_float(d1 & 0xFFFF0000u);
        acc[4] += v * __uint_as_float(d2 << 16);
        acc[5] += v * __uint_as_float(d2 & 0xFFFF0000u);
        acc[6] += v * __uint_as_float(d3 << 16);
        acc[7] += v * __uint_as_float(d3 & 0xFFFF0000u);
    }

    #pragma unroll
    for (int j = 0; j < 8; ++j) {
        acc[j] += __shfl_xor(acc[j], 16);
        acc[j] += __shfl_xor(acc[j], 32);
    }

    if (lane < 16) {
        float* op = out + (size_t)row * D + lane * 8;
        *(float4*)(op)     = make_float4(acc[0], acc[1], acc[2], acc[3]);
        *(float4*)(op + 4) = make_float4(acc[4], acc[5], acc[6], acc[7]);
    }
}

// ---------------------------------------------------------------------------
// Fallback (ws too small): atomic scatter
// ---------------------------------------------------------------------------
__global__ __launch_bounds__(256) void scatter_edges(
    const int* __restrict__ er, const int* __restrict__ ec,
    const float* __restrict__ ev, const __hip_bfloat16* __restrict__ h,
    float* __restrict__ out, int n_edges)
{
    int gw   = (blockIdx.x * 256 + threadIdx.x) >> 6;
    int lane = threadIdx.x & 63;
    if (gw >= n_edges) return;
    int r = er[gw];
    int c = ec[gw];
    float v = ev[gw];
    unsigned hv = *(const unsigned*)(h + (size_t)c * D + lane * 2);
    float* op = out + (size_t)r * D + lane * 2;
    atomicAdd(op,     v * __uint_as_float(hv << 16));
    atomicAdd(op + 1, v * __uint_as_float(hv & 0xFFFF0000u));
}

extern "C" void kernel_launch(void* const* d_in, const int* in_sizes, int n_in,
                              void* d_out, int out_size, void* d_ws, size_t ws_size,
                              hipStream_t stream) {
    const float* x  = (const float*)d_in[0];
    const int*   er = (const int*)d_in[1];
    const int*   ec = (const int*)d_in[2];
    const float* ev = (const float*)d_in[3];
    const float* W  = (const float*)d_in[4];
    const float* Wg = (const float*)d_in[5];
    const float* bg = (const float*)d_in[6];
    float* out = (float*)d_out;

    const int n_nodes = in_sizes[0] / D;
    const int n_edges = in_sizes[1];
    const int nbkt = (n_nodes + 255) >> 8;

    char* ws = (char*)d_ws;
    size_t off = 0;
    auto alloc = [&](size_t bytes) {
        char* p = ws + off;
        off += (bytes + 15) & ~size_t(15);
        return p;
    };
    __hip_bfloat16* h = (__hip_bfloat16*)alloc((size_t)n_nodes * D * sizeof(__hip_bfloat16));
    unsigned short* wt_sw = (unsigned short*)alloc((size_t)D * D * sizeof(unsigned short));
    uint2* sorted   = (uint2*)alloc((size_t)n_edges * sizeof(uint2));
    int*   startArr = (int*)  alloc((size_t)(n_nodes + 1) * sizeof(int));
    int*   cnt      = (int*)  alloc((size_t)n_nodes * sizeof(int));   // | contiguous
    int*   gcursor  = (int*)  alloc(NBKT_PAD * sizeof(int));          // | single
    int*   ovf      = (int*)  alloc(NBKT_PAD * sizeof(int));          // | memset
    int*   partials = (int*)  alloc(128 * sizeof(int));
    bool have_ws = off <= ws_size;

    // W -> transposed, pre-swizzled bf16
    transpose_W<<<D * D / 256, 256, 0, stream>>>(W, wt_sw);

    // h = gate(x) * (x @ W) via MFMA
    dim3 gemm_grid((n_nodes + BM - 1) / BM);
    mfma_gemm_gate<<<gemm_grid, 256, 0, stream>>>(x, wt_sw, Wg, bg, h, n_nodes);

    if (have_ws) {
        size_t zbytes = (size_t)n_nodes * sizeof(int) + 2 * NBKT_PAD * sizeof(int);
        hipMemsetAsync(cnt, 0, zbytes, stream);
        int eb = (n_edges + 255) / 256;
        hist_rows<<<eb, 256, 0, stream>>>(er, cnt, n_edges);
        int nblk = (n_nodes + 1023) / 1024;
        scan_pass1<<<nblk, 256, 0, stream>>>(cnt, partials, n_nodes);
        scan_pass2<<<1, 64, 0, stream>>>(partials, nblk);
        scan_pass3<<<nblk, 256, 0, stream>>>(cnt, partials, startArr, n_nodes, n_edges);
        int cb = (n_edges + CHUNK - 1) / CHUNK;
        bin_pass<<<cb, 256, 0, stream>>>(er, ec, ev, startArr, gcursor, sorted, n_edges, nbkt);
        fine_sort<<<nbkt, 256, 0, stream>>>(startArr, sorted, ovf, n_nodes);
        int rb = (n_nodes * 64 + 255) / 256;
        gather_rows<<<rb, 256, 0, stream>>>(startArr, sorted, ovf, h, out, n_nodes);
    } else {
        hipMemsetAsync(d_out, 0, (size_t)out_size * sizeof(float), stream);
        int blocks = (n_edges + 3) / 4;
        scatter_edges<<<blocks, 256, 0, stream>>>(er, ec, ev, h, out, n_edges);
    }
}